// Round 13
// baseline (358.754 us; speedup 1.0000x reference)
//
#include <hip/hip_runtime.h>
#include <stdint.h>

#define NEGF  (-1e30f)
#define LOG2E 1.4426950408889634f
#define LN2F  0.6931471805599453f

__device__ __forceinline__ float fexp2(float x) {
#if __has_builtin(__builtin_amdgcn_exp2f)
    return __builtin_amdgcn_exp2f(x);
#else
    return exp2f(x);
#endif
}
__device__ __forceinline__ float flog2(float x) {
#if __has_builtin(__builtin_amdgcn_logf)
    return __builtin_amdgcn_logf(x);
#else
    return log2f(x);
#endif
}
__device__ __forceinline__ float lse2(float a, float b) {
    float m  = fmaxf(a, b);
    float mn = fminf(a, b);
    return m + flog2(1.0f + fexp2(mn - m));
}

// DPP lane shifts (VALU-only; no lgkmcnt).
__device__ __forceinline__ float dpp_shr1(float x, float fill) {
    int r = __builtin_amdgcn_update_dpp(__float_as_int(fill), __float_as_int(x),
                                        0x138, 0xf, 0xf, false);
    return __int_as_float(r);
}
__device__ __forceinline__ float dpp_shl1(float x, float fill) {
    int r = __builtin_amdgcn_update_dpp(__float_as_int(fill), __float_as_int(x),
                                        0x130, 0xf, 0xf, false);
    return __int_as_float(r);
}

// ---- compact-row LDS ring ---------------------------------------------------
// Compact row (written by ctc_gather): c[0]=lp[blank], c[1+k]=lp[tgt[k]]
// k=0..127 (clamped to blank past len_t), c[129]=blank (lane-63 o5 pad).
// 16 slots x 1KB = 16KB LDS. ONE global_load_lds width=16 per row
// (64 lanes x 16B = 1KB). Cuts the scanning CU's traffic 4KB -> 1KB per step —
// the per-CU delivery cap (~11 B/cyc/CU: r10 scan 26 GB/s/CU == harness fill
// 26 GB/s/CU == m13 copy/256) was the wall.
// vmcnt(11): row read 4 steps ahead (staged 12 stage-instrs earlier) has landed.
#define VMW "s_waitcnt vmcnt(11)"

__device__ __forceinline__ void stage_row_c(const float* src, float* dst)
{
    const int lane = threadIdx.x;
    const float* g = src + (lane << 2);              // 16B per lane
    __builtin_amdgcn_global_load_lds((const __attribute__((address_space(1))) void*)(g),
        (__attribute__((address_space(3))) void*)(dst), 16, 0, 0);
}

// Opaque LDS gathers (compiler cannot insert a draining wait). m0=-1 restored
// (global_load_lds lowering clobbers m0 with the LDS base).
__device__ __forceinline__ void lds_read3(uint32_t sb, uint32_t o1, uint32_t o3,
                                          float& eb, float& e1, float& e3)
{
    asm volatile("s_mov_b32 m0, -1\n\t"
                 "ds_read_b32 %0, %3\n\t"
                 "ds_read_b32 %1, %4\n\t"
                 "ds_read_b32 %2, %5"
                 : "=&v"(eb), "=&v"(e1), "=&v"(e3)
                 : "v"(sb), "v"(sb + o1), "v"(sb + o3)
                 : "memory");
}
__device__ __forceinline__ void lds_read4(uint32_t sb, uint32_t o1, uint32_t o3, uint32_t o5,
                                          float& eb, float& e1, float& e3, float& e5)
{
    asm volatile("s_mov_b32 m0, -1\n\t"
                 "ds_read_b32 %0, %4\n\t"
                 "ds_read_b32 %1, %5\n\t"
                 "ds_read_b32 %2, %6\n\t"
                 "ds_read_b32 %3, %7"
                 : "=&v"(eb), "=&v"(e1), "=&v"(e3), "=&v"(e5)
                 : "v"(sb), "v"(sb + o1), "v"(sb + o3), "v"(sb + o5)
                 : "memory");
}

// Counted lgkm waits tied to the prefetched registers (anti-hoist).
#define LGKM_WAIT3(c, x0, x1, x2) \
    asm volatile("s_waitcnt lgkmcnt(" #c ")" : "+v"(x0), "+v"(x1), "+v"(x2) :: "memory")
#define LGKM_WAIT4(c, x0, x1, x2, x3) \
    asm volatile("s_waitcnt lgkmcnt(" #c ")" : "+v"(x0), "+v"(x1), "+v"(x2), "+v"(x3) :: "memory")

// ---- PER-LANE exponent renorm (every 8 steps) — HW-validated r10 -----------
#define RENORM_LANE(x0, x1, x2, x3, DPPC)                                     \
  do {                                                                        \
    float m_ = fmaxf(fmaxf(x0, x1), fmaxf(x2, x3));                           \
    int   ei_ = (__float_as_int(m_) >> 23) & 0xff;                            \
    bool  z_  = (m_ == 0.0f);                                                 \
    float sc_ = z_ ? 1.0f : ((ei_ != 0) ? __int_as_float((254 - ei_) << 23)   \
                                        : __int_as_float(253 << 23));         \
    int   d_  = z_ ? 0 : ((ei_ != 0) ? (ei_ - 127) : -126);                   \
    int   eu_ = esum + d_;                                                    \
    int   en_ = __builtin_amdgcn_update_dpp(eu_, eu_, (DPPC), 0xf, 0xf, false);\
    esum = z_ ? en_ : eu_;                        /* zero lane adopts nbr */  \
    x0 *= sc_; x1 *= sc_; x2 *= sc_; x3 *= sc_;                               \
    int   ep_ = __builtin_amdgcn_update_dpp(esum, esum, (DPPC), 0xf, 0xf, false);\
    int   ce_ = ep_ - esum;                                                   \
    ce_ = ce_ < -126 ? -126 : (ce_ > 126 ? 126 : ce_);                        \
    cross = __int_as_float((ce_ + 127) << 23);                                \
  } while (0)

// =====================  parallel gather / compaction  =======================
// All 256 CUs stream the 192MB lp once and emit 48MB compact rows. 1KB row
// stride, buffer in d_ws (L3-resident for the scan).
__global__ __launch_bounds__(128)
void ctc_gather(const float* __restrict__ lp, const int* __restrict__ tgt,
                const int* __restrict__ tlen, float* __restrict__ cbuf,
                int T, int N, int C, int L)
{
    const int TILES = (T + 31) >> 5;
    const int nb    = blockIdx.x / TILES;
    const int tile  = blockIdx.x % TILES;
    const int tid   = threadIdx.x;                   // 0..127
    const int len_t = tlen[nb];
    const int idx   = (tid < len_t && tid < L) ? tgt[(long)nb * L + tid] : 0;
    int t0 = tile << 5, t1 = t0 + 32; if (t1 > T) t1 = T;
    const long  NC = (long)N * C;
    const float* p = lp + (long)nb * C;
    float*      cb = cbuf + (long)nb * T * 256;
    for (int t = t0; t < t1; ++t) {
        float v = p[(long)t * NC + idx];             // gather
        float* crow = cb + ((long)t << 8);
        crow[1 + tid] = v;                           // coalesced 128-float store
        if (tid == 0) {
            float bl = p[(long)t * NC];              // blank
            crow[0]   = bl;
            crow[129] = bl;                          // pad: getT(128) clamps to blank
        }
    }
}

// ==========================  serial scan (r10 numerics)  ====================
// One wave per (utterance, direction). Lane i owns ext states 4i..4i+3.
// LINEAR-domain, blank-normalized, per-lane exponent tracking. Reads the
// compact rows: eb at slot+0 (uniform), e1 at 8*lane+4, e3 +4, e5 +8.
__global__ __launch_bounds__(64, 1)
void ctc_scan(const float* __restrict__ lp, const float* __restrict__ cbuf,
              const int* __restrict__ tgt, const int* __restrict__ ilen,
              const int* __restrict__ tlen,
              float* __restrict__ wsA, float* __restrict__ wsB,
              int T, int N, int C, int L)
{
    __shared__ float ring[16 * 256];                 // 16 KB

    const int  b      = blockIdx.x;
    const bool is_fwd = (b < N);
    const int  n      = is_fwd ? b : (b - N);
    const int  lane   = threadIdx.x;
    const int  len_t  = tlen[n];
    const int  len_in = ilen[n];
    const int  tm     = (len_in - 1) >> 1;
    const int  send   = 2 * len_t;

    const long tb = (long)n * L;
    auto getT = [&](int k) -> int {
        return (k >= 0 && k < len_t) ? tgt[tb + k] : 0;
    };
    const int lm1 = getT(2 * lane - 1);
    const int l1  = getT(2 * lane);
    const int l2  = getT(2 * lane + 1);
    const int l3  = getT(2 * lane + 2);
    const uint32_t o1 = ((uint32_t)lane << 3) + 4;   // c[1+2*lane]
    const uint32_t o3 = o1 + 4;                      // c[2+2*lane]
    const uint32_t o5 = o1 + 8;                      // c[3+2*lane]
    const bool skip1 = (lane > 0) && (l1 != lm1);
    const bool skip3 = (l2 != l1);
    const bool skip5 = (l3 != l2);
    const int  s0 = 4 * lane;

    const float* row0    = lp + (long)n * C;
    const float* crow0   = cbuf + (long)n * T * 256; // compact rows, 256-f stride
    const uint32_t ringb =
        (uint32_t)(uintptr_t)(const __attribute__((address_space(3))) void*)ring;

    int    esum  = 0;
    float  cross = 1.0f;
    double dsum  = 0.0;

    if (is_fwd) {
        float eb0 = row0[0];
        float e10 = row0[l1];
        asm volatile("s_waitcnt vmcnt(0)" : "+v"(eb0), "+v"(e10) :: "memory");
        dsum = (double)eb0;
        float a0 = (lane == 0) ? 1.0f : 0.0f;
        float a1 = (lane == 0 && 1 <= send) ? fexp2((e10 - eb0) * LOG2E) : 0.0f;
        float a2 = 0.0f, a3 = 0.0f;
        float p3 = 0.0f;

        const int nsteps = tm;
        const int lim    = len_in - 1;
        for (int j = 0; j < 15; ++j) {               // prologue: steps 0..14
            int r = 1 + j; if (r > lim) r = lim;
            stage_row_c(crow0 + ((long)r << 8), ring + (j << 8));
        }
        int rr = (16 > lim) ? lim : 16;
        const float* pstage = crow0 + ((long)rr << 8);

        asm volatile(VMW ::: "memory");              // rows for steps 0..3 landed
        float rb0, r1_0, r3_0, rb1, r1_1, r3_1;
        float rb2, r1_2, r3_2, rb3, r1_3, r3_3;
        lds_read3(ringb,        o1, o3, rb0, r1_0, r3_0);
        lds_read3(ringb + 1024, o1, o3, rb1, r1_1, r3_1);
        lds_read3(ringb + 2048, o1, o3, rb2, r1_2, r3_2);
        lds_read3(ringb + 3072, o1, o3, rb3, r1_3, r3_3);

#define FSLOT(u, s)                                                            \
  do {                                                                         \
    stage_row_c(pstage, ring + ((((u) + 15) & 15) << 8));                      \
    { int adv = (rr < lim); rr += adv; pstage += adv ? 256 : 0; }              \
    asm volatile(VMW ::: "memory");                                            \
    LGKM_WAIT3(9, rb##s, r1_##s, r3_##s);                                      \
    float cb = rb##s, c1v = r1_##s, c3v = r3_##s;                              \
    lds_read3(ringb + ((((u) + 4) & 15) << 10), o1, o3, rb##s, r1_##s, r3_##s);\
    float rv1 = fexp2((c1v - cb) * LOG2E);                                     \
    float rv3 = fexp2((c3v - cb) * LOG2E);                                     \
    dsum += (double)cb;                                                        \
    float n0 = a0 + p3;                                                        \
    float n1 = (a1 + a0 + (skip1 ? p3 : 0.0f)) * rv1;                          \
    float n2 = a2 + a1;                                                        \
    float n3 = (a3 + a2 + (skip3 ? a1 : 0.0f)) * rv3;                          \
    a0 = n0; a1 = n1; a2 = n2; a3 = n3;                                        \
    p3 = dpp_shr1(a3, 0.0f) * cross;                                           \
  } while (0)

#define RENORM_F() do { RENORM_LANE(a0, a1, a2, a3, 0x138);                    \
                        p3 = dpp_shr1(a3, 0.0f) * cross; } while (0)

        int i = 0;
        while (i + 16 <= nsteps) {
            FSLOT(0,0);  FSLOT(1,1);  FSLOT(2,2);  FSLOT(3,3);
            FSLOT(4,0);  FSLOT(5,1);  FSLOT(6,2);  FSLOT(7,3);
            RENORM_F();
            FSLOT(8,0);  FSLOT(9,1);  FSLOT(10,2); FSLOT(11,3);
            FSLOT(12,0); FSLOT(13,1); FSLOT(14,2); FSLOT(15,3);
            RENORM_F();
            i += 16;
        }
        asm volatile("s_waitcnt vmcnt(0) lgkmcnt(0)"    // liveness drain
                     :: "v"(rb0), "v"(r1_0), "v"(r3_0), "v"(rb1), "v"(r1_1), "v"(r3_1),
                        "v"(rb2), "v"(r1_2), "v"(r3_2), "v"(rb3), "v"(r1_3), "v"(r3_3)
                     : "memory");
        for (; i < nsteps; ++i) {
            float cb, c1v, c3v;
            lds_read3(ringb + (uint32_t)((i & 15) << 10), o1, o3, cb, c1v, c3v);
            LGKM_WAIT3(0, cb, c1v, c3v);
            float rv1 = fexp2((c1v - cb) * LOG2E);
            float rv3 = fexp2((c3v - cb) * LOG2E);
            dsum += (double)cb;
            float n0 = a0 + p3;
            float n1 = (a1 + a0 + (skip1 ? p3 : 0.0f)) * rv1;
            float n2 = a2 + a1;
            float n3 = (a3 + a2 + (skip3 ? a1 : 0.0f)) * rv3;
            a0 = n0; a1 = n1; a2 = n2; a3 = n3;
            p3 = dpp_shr1(a3, 0.0f) * cross;
            if ((i & 7) == 7) RENORM_F();
        }
        float S  = (float)(dsum * 1.4426950408889634);
        float fe = (float)esum;
        float w0 = fmaxf(flog2(a0) + fe + S, NEGF);
        float w1 = fmaxf(flog2(a1) + fe + S, NEGF);
        float w2 = fmaxf(flog2(a2) + fe + S, NEGF);
        float w3 = fmaxf(flog2(a3) + fe + S, NEGF);
        *((float4*)(wsA + (long)n * 256) + lane) = make_float4(w0, w1, w2, w3);
#undef FSLOT
#undef RENORM_F
    } else {
        float b0 = (s0     == send || s0     == send - 1) ? 1.0f : 0.0f;
        float b1 = (s0 + 1 == send || s0 + 1 == send - 1) ? 1.0f : 0.0f;
        float b2 = (s0 + 2 == send || s0 + 2 == send - 1) ? 1.0f : 0.0f;
        float b3 = (s0 + 3 == send || s0 + 3 == send - 1) ? 1.0f : 0.0f;
        float q0 = dpp_shl1(b0, 0.0f);
        float q1 = dpp_shl1(b1, 0.0f);

        const int nsteps = len_in - 1 - tm;
        for (int j = 0; j < 15; ++j) {
            int r = len_in - 1 - j; if (r < 0) r = 0;
            stage_row_c(crow0 + ((long)r << 8), ring + (j << 8));
        }
        int rr = len_in - 16; if (rr < 0) rr = 0;
        const float* pstage = crow0 + ((long)rr << 8);

        asm volatile(VMW ::: "memory");
        float rb0, r1_0, r3_0, r5_0, rb1, r1_1, r3_1, r5_1;
        float rb2, r1_2, r3_2, r5_2, rb3, r1_3, r3_3, r5_3;
        lds_read4(ringb,        o1, o3, o5, rb0, r1_0, r3_0, r5_0);
        lds_read4(ringb + 1024, o1, o3, o5, rb1, r1_1, r3_1, r5_1);
        lds_read4(ringb + 2048, o1, o3, o5, rb2, r1_2, r3_2, r5_2);
        lds_read4(ringb + 3072, o1, o3, o5, rb3, r1_3, r3_3, r5_3);

#define BSLOT(u, s)                                                            \
  do {                                                                         \
    stage_row_c(pstage, ring + ((((u) + 15) & 15) << 8));                      \
    { int adv = (rr > 0); rr -= adv; pstage -= adv ? 256 : 0; }                \
    asm volatile(VMW ::: "memory");                                            \
    LGKM_WAIT4(12, rb##s, r1_##s, r3_##s, r5_##s);                             \
    float cb = rb##s, c1v = r1_##s, c3v = r3_##s, c5v = r5_##s;                \
    lds_read4(ringb + ((((u) + 4) & 15) << 10), o1, o3, o5,                    \
              rb##s, r1_##s, r3_##s, r5_##s);                                  \
    float rv1 = fexp2((c1v - cb) * LOG2E);                                     \
    float rv3 = fexp2((c3v - cb) * LOG2E);                                     \
    float rv5 = fexp2((c5v - cb) * LOG2E);                                     \
    dsum += (double)cb;                                                        \
    float g1 = b1 * rv1, g3 = b3 * rv3;                                        \
    float n0 = b0 + g1;                                                        \
    float n1 = g1 + b2 + (skip3 ? g3 : 0.0f);                                  \
    float n2 = b2 + g3;                                                        \
    float n3 = g3 + q0 + (skip5 ? q1 * rv5 : 0.0f);                            \
    b0 = n0; b1 = n1; b2 = n2; b3 = n3;                                        \
    q0 = dpp_shl1(b0, 0.0f) * cross;                                           \
    q1 = dpp_shl1(b1, 0.0f) * cross;                                           \
  } while (0)

#define RENORM_B() do { RENORM_LANE(b0, b1, b2, b3, 0x130);                    \
                        q0 = dpp_shl1(b0, 0.0f) * cross;                       \
                        q1 = dpp_shl1(b1, 0.0f) * cross; } while (0)

        int i = 0;
        while (i + 16 <= nsteps) {
            BSLOT(0,0);  BSLOT(1,1);  BSLOT(2,2);  BSLOT(3,3);
            BSLOT(4,0);  BSLOT(5,1);  BSLOT(6,2);  BSLOT(7,3);
            RENORM_B();
            BSLOT(8,0);  BSLOT(9,1);  BSLOT(10,2); BSLOT(11,3);
            BSLOT(12,0); BSLOT(13,1); BSLOT(14,2); BSLOT(15,3);
            RENORM_B();
            i += 16;
        }
        asm volatile("s_waitcnt vmcnt(0) lgkmcnt(0)"
                     :: "v"(rb0), "v"(r1_0), "v"(r3_0), "v"(r5_0),
                        "v"(rb1), "v"(r1_1), "v"(r3_1), "v"(r5_1),
                        "v"(rb2), "v"(r1_2), "v"(r3_2), "v"(r5_2),
                        "v"(rb3), "v"(r1_3), "v"(r3_3), "v"(r5_3)
                     : "memory");
        for (; i < nsteps; ++i) {
            float cb, c1v, c3v, c5v;
            lds_read4(ringb + (uint32_t)((i & 15) << 10), o1, o3, o5,
                      cb, c1v, c3v, c5v);
            LGKM_WAIT4(0, cb, c1v, c3v, c5v);
            float rv1 = fexp2((c1v - cb) * LOG2E);
            float rv3 = fexp2((c3v - cb) * LOG2E);
            float rv5 = fexp2((c5v - cb) * LOG2E);
            dsum += (double)cb;
            float g1 = b1 * rv1, g3 = b3 * rv3;
            float n0 = b0 + g1;
            float n1 = g1 + b2 + (skip3 ? g3 : 0.0f);
            float n2 = b2 + g3;
            float n3 = g3 + q0 + (skip5 ? q1 * rv5 : 0.0f);
            b0 = n0; b1 = n1; b2 = n2; b3 = n3;
            q0 = dpp_shl1(b0, 0.0f) * cross;
            q1 = dpp_shl1(b1, 0.0f) * cross;
            if ((i & 7) == 7) RENORM_B();
        }
        float S  = (float)(dsum * 1.4426950408889634);
        float fe = (float)esum;
        float w0 = fmaxf(flog2(b0) + fe + S, NEGF);
        float w1 = fmaxf(flog2(b1) + fe + S, NEGF);
        float w2 = fmaxf(flog2(b2) + fe + S, NEGF);
        float w3 = fmaxf(flog2(b3) + fe + S, NEGF);
        *((float4*)(wsB + (long)n * 256) + lane) = make_float4(w0, w1, w2, w3);
#undef BSLOT
#undef RENORM_B
    }
}

// tot_n = logsumexp_s( alpha[tm][s] + beta[tm][s] );  out += -tot_n if finite
__global__ __launch_bounds__(64, 1)
void ctc_combine(const float* __restrict__ wsA, const float* __restrict__ wsB,
                 float* __restrict__ out)
{
    const int n = blockIdx.x;
    const int lane = threadIdx.x;
    const float4 A = *((const float4*)(wsA + (long)n * 256) + lane);
    const float4 B = *((const float4*)(wsB + (long)n * 256) + lane);
    float v = lse2(lse2(A.x + B.x, A.y + B.y), lse2(A.z + B.z, A.w + B.w));
    #pragma unroll
    for (int off = 1; off < 64; off <<= 1) {
        float o = __shfl_xor(v, off, 64);
        v = lse2(v, o);
    }
    if (lane == 0) {
        float tot = v * LN2F;
        if (tot > -1e29f) atomicAdd(out, -tot);
    }
}

extern "C" void kernel_launch(void* const* d_in, const int* in_sizes, int n_in,
                              void* d_out, int out_size, void* d_ws, size_t ws_size,
                              hipStream_t stream) {
    const float* lp      = (const float*)d_in[0];
    const int*   targets = (const int*)d_in[1];
    const int*   in_len  = (const int*)d_in[2];
    const int*   tgt_len = (const int*)d_in[3];
    const int N = in_sizes[2];
    const int L = in_sizes[1] / N;
    const int C = 1024;                              // fixed by the reference problem
    const int T = (int)((long)in_sizes[0] / ((long)N * C));

    float* out  = (float*)d_out;
    float* wsA  = (float*)d_ws;                      // N*256 floats
    float* wsB  = wsA + (long)N * 256;               // N*256 floats
    float* cbuf = wsB + (long)N * 256;               // N*T*256 floats (~48 MB)

    const int TILES = (T + 31) >> 5;

    hipMemsetAsync(out, 0, sizeof(float), stream);
    ctc_gather<<<N * TILES, 128, 0, stream>>>(lp, targets, tgt_len, cbuf,
                                              T, N, C, L);
    ctc_scan<<<2 * N, 64, 0, stream>>>(lp, cbuf, targets, in_len, tgt_len,
                                       wsA, wsB, T, N, C, L);
    ctc_combine<<<N, 64, 0, stream>>>(wsA, wsB, out);
}